// Round 1
// baseline (227.296 us; speedup 1.0000x reference)
//
#include <hip/hip_runtime.h>
#include <hip/hip_bf16.h>

#define BATCH 8192
#define KDIM  2048   // NUM_INPUTS*UNITS
#define NDIM  2048   // NUM_OUTPUTS*UNITS
#define BM 128
#define BN 128
#define BK 32

typedef short bf16x8 __attribute__((ext_vector_type(8)));
typedef float f32x4  __attribute__((ext_vector_type(4)));

__device__ __forceinline__ unsigned short f2bf(float f) {
    unsigned int u = __float_as_uint(f);
    u = u + 0x7fffu + ((u >> 16) & 1u);   // round-to-nearest-even
    return (unsigned short)(u >> 16);
}

// ---------- pack A: x fp32 [8192][2048] -> bf16 ----------
__global__ __launch_bounds__(256) void pack_a(const float* __restrict__ x,
                                              short* __restrict__ a) {
    int h = blockIdx.x * 256 + threadIdx.x;      // 2M chunks of 8 elements
    const f32x4* xv = (const f32x4*)x;
    f32x4 v0 = xv[(size_t)h * 2];
    f32x4 v1 = xv[(size_t)h * 2 + 1];
    bf16x8 r;
    r[0] = (short)f2bf(v0[0]); r[1] = (short)f2bf(v0[1]);
    r[2] = (short)f2bf(v0[2]); r[3] = (short)f2bf(v0[3]);
    r[4] = (short)f2bf(v1[0]); r[5] = (short)f2bf(v1[1]);
    r[6] = (short)f2bf(v1[2]); r[7] = (short)f2bf(v1[3]);
    ((bf16x8*)a)[h] = r;
}

// ---------- pack B: Bp[j][k] = bf16( z[o,n] * T[o,n,u,v] ), j=o*256+v, k=n*256+u ----------
__global__ __launch_bounds__(256) void pack_b(const float* __restrict__ T,
                                              const float* __restrict__ u_param,
                                              const float* __restrict__ alpha,
                                              short* __restrict__ bp) {
    int g = blockIdx.x * 256 + threadIdx.x;      // 512K tasks: one 8-wide k-chunk
    int j = g >> 8, c = g & 255;                 // j in [0,2048), c = k-chunk in [0,256)
    int o = j >> 8, v = j & 255;
    int n = c >> 5, u0 = (c & 31) * 8;
    float up = u_param[o * 8 + n];
    float t  = logf(up) - logf(1.0f - up) + logf(alpha[0]) * (1.0f / 0.9f);
    float s  = 1.0f / (1.0f + expf(-t));
    float z  = s * 1.2f - 0.1f;                  // (EPSILON-GAMMA)=1.2, +GAMMA=-0.1
    z = fminf(fmaxf(z, 0.0f), 1.0f);
    const float* tp = T + (((size_t)(o * 8 + n)) << 16) + (size_t)u0 * 256 + v;
    bf16x8 r;
#pragma unroll
    for (int i = 0; i < 8; ++i) r[i] = (short)f2bf(z * tp[(size_t)i * 256]);
    ((bf16x8*)bp)[(size_t)j * 256 + c] = r;      // coalesced 16B writes along k
}

// ---------- GEMM: C[8192][2048] = A[8192][2048] x Bp[2048][2048]^T (bf16 MFMA) ----------
__global__ __launch_bounds__(256, 2) void gemm(const short* __restrict__ A,
                                               const short* __restrict__ B,
                                               float* __restrict__ C) {
    __shared__ __align__(16) short As[2][BM * BK];
    __shared__ __align__(16) short Bs[2][BN * BK];

    int tid = threadIdx.x;
    int bid = blockIdx.x;
    // XCD-aware bijective swizzle (1024 % 8 == 0)
    int wg = (bid & 7) * 128 + (bid >> 3);
    int bx = wg & 15, by = wg >> 4;
    int bm = by * BM, bn = bx * BN;

    int wid = tid >> 6, lane = tid & 63;
    int wr = wid >> 1, wc = wid & 1;             // 2x2 wave grid, 64x64 per wave
    int lrow = lane & 15, lk = lane >> 4;

    f32x4 acc[4][4] = {};

    auto stage = [&](int buf, int kt) {
#pragma unroll
        for (int i = 0; i < 2; ++i) {
            int c = i * 256 + tid;               // 512 chunks of 16B per tile
            int r = c >> 2, cw = c & 3;
            const short* ga = A + (size_t)(bm + r) * KDIM + kt * BK + cw * 8;
            __builtin_amdgcn_global_load_lds(
                (const __attribute__((address_space(1))) void*)ga,
                (__attribute__((address_space(3))) void*)&As[buf][c * 8], 16, 0, 0);
            const short* gb = B + (size_t)(bn + r) * KDIM + kt * BK + cw * 8;
            __builtin_amdgcn_global_load_lds(
                (const __attribute__((address_space(1))) void*)gb,
                (__attribute__((address_space(3))) void*)&Bs[buf][c * 8], 16, 0, 0);
        }
    };

    stage(0, 0);
    __syncthreads();
    int cur = 0;
    const int NT = KDIM / BK;                    // 64
    for (int kt = 0; kt < NT; ++kt) {
        if (kt + 1 < NT) stage(cur ^ 1, kt + 1);
        bf16x8 a[4], b[4];
#pragma unroll
        for (int m = 0; m < 4; ++m)
            a[m] = *(const bf16x8*)&As[cur][(wr * 64 + m * 16 + lrow) * BK + lk * 8];
#pragma unroll
        for (int n = 0; n < 4; ++n)
            b[n] = *(const bf16x8*)&Bs[cur][(wc * 64 + n * 16 + lrow) * BK + lk * 8];
#pragma unroll
        for (int m = 0; m < 4; ++m)
#pragma unroll
            for (int n = 0; n < 4; ++n)
                acc[m][n] = __builtin_amdgcn_mfma_f32_16x16x32_bf16(a[m], b[n], acc[m][n], 0, 0, 0);
        __syncthreads();
        cur ^= 1;
    }

    // epilogue: D row=(lane>>4)*4+reg, col=lane&15  [verified m89 layout]
    int r0 = bm + wr * 64 + (lane >> 4) * 4;
    int c0 = bn + wc * 64 + lrow;
#pragma unroll
    for (int m = 0; m < 4; ++m)
#pragma unroll
        for (int n = 0; n < 4; ++n)
#pragma unroll
            for (int r = 0; r < 4; ++r)
                C[(size_t)(r0 + m * 16 + r) * NDIM + (c0 + n * 16)] = acc[m][n][r];
}

extern "C" void kernel_launch(void* const* d_in, const int* in_sizes, int n_in,
                              void* d_out, int out_size, void* d_ws, size_t ws_size,
                              hipStream_t stream) {
    const float* x       = (const float*)d_in[0];   // [8192,8,256]
    const float* alpha   = (const float*)d_in[1];   // [1]
    const float* u_param = (const float*)d_in[2];   // [8,8]
    const float* T       = (const float*)d_in[3];   // [8,8,256,256]
    float* out = (float*)d_out;                     // [8192,8,256]

    short* Abf = (short*)d_ws;                                  // 32 MiB
    short* Bp  = (short*)((char*)d_ws + (size_t)BATCH * KDIM * 2); // 8 MiB

    hipLaunchKernelGGL(pack_a, dim3((BATCH * KDIM / 8) / 256), dim3(256), 0, stream, x, Abf);
    hipLaunchKernelGGL(pack_b, dim3((NDIM * KDIM / 8) / 256), dim3(256), 0, stream,
                       T, u_param, alpha, Bp);
    hipLaunchKernelGGL(gemm, dim3((BATCH / BM) * (NDIM / BN)), dim3(256), 0, stream,
                       Abf, Bp, out);
}

// Round 3
// 193.233 us; speedup vs baseline: 1.1763x; 1.1763x over previous
//
#include <hip/hip_runtime.h>
#include <hip/hip_bf16.h>

#define BATCH 8192
#define KDIM  2048   // NUM_INPUTS*UNITS
#define NDIM  2048   // NUM_OUTPUTS*UNITS

typedef short bf16x8 __attribute__((ext_vector_type(8)));
typedef float f32x4  __attribute__((ext_vector_type(4)));

__device__ __forceinline__ unsigned short f2bf(float f) {
    unsigned int u = __float_as_uint(f);
    u = u + 0x7fffu + ((u >> 16) & 1u);   // round-to-nearest-even
    return (unsigned short)(u >> 16);
}

// ---------- pack A: x fp32 [8192][2048] -> bf16 (coalesced float4 -> bf16x8) ----------
__global__ __launch_bounds__(256) void pack_a(const float* __restrict__ x,
                                              short* __restrict__ a) {
    int h = blockIdx.x * 256 + threadIdx.x;
    const f32x4* xv = (const f32x4*)x;
    f32x4 v0 = xv[(size_t)h * 2];
    f32x4 v1 = xv[(size_t)h * 2 + 1];
    bf16x8 r;
    r[0] = (short)f2bf(v0[0]); r[1] = (short)f2bf(v0[1]);
    r[2] = (short)f2bf(v0[2]); r[3] = (short)f2bf(v0[3]);
    r[4] = (short)f2bf(v1[0]); r[5] = (short)f2bf(v1[1]);
    r[6] = (short)f2bf(v1[2]); r[7] = (short)f2bf(v1[3]);
    ((bf16x8*)a)[h] = r;
}

// ---------- pack B via LDS transpose: Bp[j][k] = bf16(z[o,n]*T[o,n,u,v]) ----------
// j=o*256+v, k=n*256+u. Reads coalesced along v (float4), writes coalesced along k (bf16x8).
__global__ __launch_bounds__(256) void pack_b(const float* __restrict__ T,
                                              const float* __restrict__ u_param,
                                              const float* __restrict__ alpha,
                                              short* __restrict__ bp) {
    __shared__ short tl[256 * 33];   // [u][v'] with +1 pad, 16.5 KiB
    int bid = blockIdx.x;            // 512 blocks: o(8) x n(8) x vchunk(8)
    int o  = bid >> 6;
    int n  = (bid >> 3) & 7;
    int v0 = (bid & 7) * 32;
    int tid = threadIdx.x;

    float up = u_param[o * 8 + n];
    float t  = logf(up) - logf(1.0f - up) + logf(alpha[0]) * (1.0f / 0.9f);
    float s  = 1.0f / (1.0f + expf(-t));
    float z  = fminf(fmaxf(s * 1.2f - 0.1f, 0.0f), 1.0f);

    const f32x4* T4 = (const f32x4*)(T + ((size_t)(o * 8 + n) << 16));
#pragma unroll
    for (int it = 0; it < 8; ++it) {
        int f = it * 256 + tid;          // float4 task
        int u = f >> 3, vv = (f & 7) * 4;
        f32x4 val = T4[(u * 256 + v0 + vv) >> 2];
#pragma unroll
        for (int j = 0; j < 4; ++j)
            tl[u * 33 + vv + j] = (short)f2bf(z * val[j]);
    }
    __syncthreads();
#pragma unroll
    for (int it = 0; it < 4; ++it) {
        int g = it * 256 + tid;
        int v = g >> 5, ch = g & 31;
        bf16x8 r;
#pragma unroll
        for (int q = 0; q < 8; ++q) r[q] = tl[(ch * 8 + q) * 33 + v];
        *(bf16x8*)&bp[(size_t)(o * 256 + v0 + v) * KDIM + n * 256 + ch * 8] = r;
    }
}

// ---------- GEMM: 256x256 tile, BK=64, 8 waves, 8-phase counted-vmcnt schedule ----------
#define SBAR() do { __builtin_amdgcn_sched_barrier(0); \
                    __builtin_amdgcn_s_barrier(); \
                    __builtin_amdgcn_sched_barrier(0); } while (0)

#define MMQ(q) do { \
    __builtin_amdgcn_s_setprio(1); \
    _Pragma("unroll") for (int mm = 0; mm < 2; ++mm) \
    _Pragma("unroll") for (int nn = 0; nn < 4; ++nn) \
    _Pragma("unroll") for (int k8 = 0; k8 < 2; ++k8) \
        acc[(q)*2 + mm][nn] = __builtin_amdgcn_mfma_f32_16x16x32_bf16( \
            afr[mm][k8], bfr[nn][k8], acc[(q)*2 + mm][nn], 0, 0, 0); \
    __builtin_amdgcn_s_setprio(0); \
} while (0)

__global__ __launch_bounds__(512, 2) void gemm(const short* __restrict__ A,
                                               const short* __restrict__ B,
                                               float* __restrict__ C) {
    // LDS: A buf0 @0, A buf1 @16384, B buf0 @32768, B buf1 @49152 (elements). 128 KiB.
    __shared__ __align__(16) short lds[65536];

    const int tid  = threadIdx.x;
    const int lane = tid & 63;
    const int wid  = tid >> 6;
    const int wr = wid >> 2, wc = wid & 3;      // 2M x 4N waves; 128x64 out each
    const int l15 = lane & 15, hi8 = (lane >> 4) * 8;
    const int sx  = ((lane >> 2) & 1) << 4;     // st_16x32 read-side XOR (elements)

    int bid = blockIdx.x;
    int wg  = (bid & 7) * 32 + (bid >> 3);      // bijective XCD swizzle (256 wgs)
    int by = wg >> 3, bx = wg & 7;
    const int bm = by * 256, bn = bx * 256;

    // staging source coords: linear LDS dest L -> swizzled global (r,c); involution
    int r_[2], c_[2];
#pragma unroll
    for (int i = 0; i < 2; ++i) {
        int L = i * 4096 + tid * 8;
        int S = L ^ (((L >> 8) & 1) << 4);
        r_[i] = S >> 6; c_[i] = S & 63;
    }

    auto stA = [&](int buf, int h, int kt) {
#pragma unroll
        for (int i = 0; i < 2; ++i) {
            const short* src = A + (size_t)(bm + h * 128 + r_[i]) * KDIM + kt * 64 + c_[i];
            __builtin_amdgcn_global_load_lds(
                (const __attribute__((address_space(1))) void*)src,
                (__attribute__((address_space(3))) void*)&lds[buf * 16384 + h * 8192 + i * 4096 + tid * 8],
                16, 0, 0);
        }
    };
    auto stB = [&](int buf, int h, int kt) {
#pragma unroll
        for (int i = 0; i < 2; ++i) {
            const short* src = B + (size_t)(bn + h * 128 + r_[i]) * KDIM + kt * 64 + c_[i];
            __builtin_amdgcn_global_load_lds(
                (const __attribute__((address_space(1))) void*)src,
                (__attribute__((address_space(3))) void*)&lds[32768 + buf * 16384 + h * 8192 + i * 4096 + tid * 8],
                16, 0, 0);
        }
    };

    f32x4  acc[8][4] = {};
    bf16x8 bfr[4][2];
    bf16x8 afr[2][2];

    auto rdB = [&](int buf) {
        int base = 32768 + buf * 16384 + (wc * 64 + l15) * 64 + hi8;
#pragma unroll
        for (int nn = 0; nn < 4; ++nn)
#pragma unroll
            for (int k8 = 0; k8 < 2; ++k8)
                bfr[nn][k8] = *(const bf16x8*)&lds[(base + nn * 1024 + k8 * 32) ^ sx];
    };
    auto rdA = [&](int buf, int q) {
        int base = buf * 16384 + (wr * 128 + q * 32 + l15) * 64 + hi8;
#pragma unroll
        for (int mm = 0; mm < 2; ++mm)
#pragma unroll
            for (int k8 = 0; k8 < 2; ++k8)
                afr[mm][k8] = *(const bf16x8*)&lds[(base + mm * 1024 + k8 * 32) ^ sx];
    };

    // ---- prologue: A(0),B(0) -> buf0; B(1) -> buf1; wait all but B(1) ----
    stA(0, 0, 0); stA(0, 1, 0);
    stB(0, 0, 0); stB(0, 1, 0);
    stB(1, 0, 1); stB(1, 1, 1);
    asm volatile("s_waitcnt vmcnt(4)" ::: "memory");
    SBAR();

    // 32 K-tiles, 2 per iteration. Stage schedule (region freed one barrier earlier):
    // P1,P2: A(t1)->Abuf1   P3,P4: B(t2)->Bbuf0   P5,P6: A(t2)->Abuf0   P7,P8: B(t3)->Bbuf1
    // vmcnt(4) at P4/P8 leaves only the 2 newest half-tiles in flight.
    for (int i = 0; i < 16; ++i) {
        int t1 = 2 * i + 1, t2 = (2 * i + 2) & 31, t3 = (2 * i + 3) & 31;
        // P1
        rdB(0); rdA(0, 0); stA(1, 0, t1);
        SBAR(); MMQ(0); SBAR();
        // P2
        rdA(0, 1); stA(1, 1, t1);
        SBAR(); MMQ(1); SBAR();
        // P3
        rdA(0, 2); stB(0, 0, t2);
        SBAR(); MMQ(2); SBAR();
        // P4
        rdA(0, 3); stB(0, 1, t2);
        SBAR(); MMQ(3);
        asm volatile("s_waitcnt vmcnt(4)" ::: "memory");
        SBAR();
        // P5
        rdB(1); rdA(1, 0); stA(0, 0, t2);
        SBAR(); MMQ(0); SBAR();
        // P6
        rdA(1, 1); stA(0, 1, t2);
        SBAR(); MMQ(1); SBAR();
        // P7
        rdA(1, 2); stB(1, 0, t3);
        SBAR(); MMQ(2); SBAR();
        // P8
        rdA(1, 3); stB(1, 1, t3);
        SBAR(); MMQ(3);
        asm volatile("s_waitcnt vmcnt(4)" ::: "memory");
        SBAR();
    }
    asm volatile("s_waitcnt vmcnt(0)" ::: "memory");

    // epilogue: C/D layout col=lane&15, row=(lane>>4)*4+reg  [m89-verified]
    int r0 = bm + wr * 128 + (lane >> 4) * 4;
    int c0 = bn + wc * 64 + l15;
#pragma unroll
    for (int m = 0; m < 8; ++m)
#pragma unroll
        for (int nn = 0; nn < 4; ++nn)
#pragma unroll
            for (int r = 0; r < 4; ++r)
                C[(size_t)(r0 + m * 16 + r) * NDIM + c0 + nn * 16] = acc[m][nn][r];
}

extern "C" void kernel_launch(void* const* d_in, const int* in_sizes, int n_in,
                              void* d_out, int out_size, void* d_ws, size_t ws_size,
                              hipStream_t stream) {
    const float* x       = (const float*)d_in[0];   // [8192,8,256]
    const float* alpha   = (const float*)d_in[1];   // [1]
    const float* u_param = (const float*)d_in[2];   // [8,8]
    const float* T       = (const float*)d_in[3];   // [8,8,256,256]
    float* out = (float*)d_out;                     // [8192,8,256]

    short* Abf = (short*)d_ws;                                     // 32 MiB
    short* Bp  = (short*)((char*)d_ws + (size_t)BATCH * KDIM * 2); // 8 MiB

    hipLaunchKernelGGL(pack_a, dim3((BATCH * KDIM / 8) / 256), dim3(256), 0, stream, x, Abf);
    hipLaunchKernelGGL(pack_b, dim3(512), dim3(256), 0, stream, T, u_param, alpha, Bp);
    hipLaunchKernelGGL(gemm, dim3((BATCH / 256) * (NDIM / 256)), dim3(512), 0, stream,
                       Abf, Bp, out);
}

// Round 4
// 186.809 us; speedup vs baseline: 1.2167x; 1.0344x over previous
//
#include <hip/hip_runtime.h>
#include <hip/hip_bf16.h>

#define BATCH 8192
#define KDIM  2048   // NUM_INPUTS*UNITS
#define NDIM  2048   // NUM_OUTPUTS*UNITS

typedef short bf16x8 __attribute__((ext_vector_type(8)));
typedef float f32x4  __attribute__((ext_vector_type(4)));

__device__ __forceinline__ unsigned short f2bf(float f) {
    unsigned int u = __float_as_uint(f);
    u = u + 0x7fffu + ((u >> 16) & 1u);   // round-to-nearest-even
    return (unsigned short)(u >> 16);
}

// ---------- pack A: x fp32 [8192][2048] -> bf16 (coalesced float4 -> bf16x8) ----------
__global__ __launch_bounds__(256) void pack_a(const float* __restrict__ x,
                                              short* __restrict__ a) {
    int h = blockIdx.x * 256 + threadIdx.x;
    const f32x4* xv = (const f32x4*)x;
    f32x4 v0 = xv[(size_t)h * 2];
    f32x4 v1 = xv[(size_t)h * 2 + 1];
    bf16x8 r;
    r[0] = (short)f2bf(v0[0]); r[1] = (short)f2bf(v0[1]);
    r[2] = (short)f2bf(v0[2]); r[3] = (short)f2bf(v0[3]);
    r[4] = (short)f2bf(v1[0]); r[5] = (short)f2bf(v1[1]);
    r[6] = (short)f2bf(v1[2]); r[7] = (short)f2bf(v1[3]);
    ((bf16x8*)a)[h] = r;
}

// ---------- pack B via LDS transpose: Bp[j][k] = bf16(z[o,n]*T[o,n,u,v]) ----------
// j=o*256+v, k=n*256+u. Reads coalesced along v (float4), writes coalesced along k (bf16x8).
__global__ __launch_bounds__(256) void pack_b(const float* __restrict__ T,
                                              const float* __restrict__ u_param,
                                              const float* __restrict__ alpha,
                                              short* __restrict__ bp) {
    __shared__ short tl[256 * 33];   // [u][v'] with +1 pad, 16.5 KiB
    int bid = blockIdx.x;            // 512 blocks: o(8) x n(8) x vchunk(8)
    int o  = bid >> 6;
    int n  = (bid >> 3) & 7;
    int v0 = (bid & 7) * 32;
    int tid = threadIdx.x;

    float up = u_param[o * 8 + n];
    float t  = logf(up) - logf(1.0f - up) + logf(alpha[0]) * (1.0f / 0.9f);
    float s  = 1.0f / (1.0f + expf(-t));
    float z  = fminf(fmaxf(s * 1.2f - 0.1f, 0.0f), 1.0f);

    const f32x4* T4 = (const f32x4*)(T + ((size_t)(o * 8 + n) << 16));
#pragma unroll
    for (int it = 0; it < 8; ++it) {
        int f = it * 256 + tid;          // float4 task
        int u = f >> 3, vv = (f & 7) * 4;
        f32x4 val = T4[(u * 256 + v0 + vv) >> 2];
#pragma unroll
        for (int j = 0; j < 4; ++j)
            tl[u * 33 + vv + j] = (short)f2bf(z * val[j]);
    }
    __syncthreads();
#pragma unroll
    for (int it = 0; it < 4; ++it) {
        int g = it * 256 + tid;
        int v = g >> 5, ch = g & 31;
        bf16x8 r;
#pragma unroll
        for (int q = 0; q < 8; ++q) r[q] = tl[(ch * 8 + q) * 33 + v];
        *(bf16x8*)&bp[(size_t)(o * 256 + v0 + v) * KDIM + n * 256 + ch * 8] = r;
    }
}

// ---------- GEMM: 256x256 tile, BK=64, 8 waves, 8-phase counted-vmcnt schedule ----------
// LDS swizzle: element_addr ^= (row&7)<<3  (byte bits 4-6 ^= row bits 0-2) -> each
// ds_read_b128 spreads 64 lanes over all 8 16B bank-slots, 8 accesses/slot = BW floor.
// Same involution pre-applied to the global_load_lds SOURCE (linear LDS dest, rule 21).
#define SBAR() do { __builtin_amdgcn_sched_barrier(0); \
                    __builtin_amdgcn_s_barrier(); \
                    __builtin_amdgcn_sched_barrier(0); } while (0)

#define MMQ(q) do { \
    __builtin_amdgcn_s_setprio(1); \
    _Pragma("unroll") for (int mm = 0; mm < 2; ++mm) \
    _Pragma("unroll") for (int nn = 0; nn < 4; ++nn) \
    _Pragma("unroll") for (int k8 = 0; k8 < 2; ++k8) \
        acc[(q)*2 + mm][nn] = __builtin_amdgcn_mfma_f32_16x16x32_bf16( \
            afr[mm][k8], bfr[nn][k8], acc[(q)*2 + mm][nn], 0, 0, 0); \
    __builtin_amdgcn_s_setprio(0); \
} while (0)

__global__ __launch_bounds__(512, 2) void gemm(const short* __restrict__ A,
                                               const short* __restrict__ B,
                                               float* __restrict__ C) {
    // LDS: A buf0 @0, A buf1 @16384, B buf0 @32768, B buf1 @49152 (elements). 128 KiB.
    __shared__ __align__(16) short lds[65536];

    const int tid  = threadIdx.x;
    const int lane = tid & 63;
    const int wid  = tid >> 6;
    const int wr = wid >> 2, wc = wid & 3;      // 2M x 4N waves; 128x64 out each
    const int l15 = lane & 15, hi8 = (lane >> 4) * 8;
    const int sx  = (lane & 7) << 3;            // read-side XOR: (row&7)<<3 elements

    int bid = blockIdx.x;
    int wg  = (bid & 7) * 32 + (bid >> 3);      // bijective XCD swizzle (256 wgs)
    int by = wg >> 3, bx = wg & 7;
    const int bm = by * 256, bn = bx * 256;

    // staging source coords: linear LDS dest L -> swizzled global (r,c); involution
    int r_[2], c_[2];
#pragma unroll
    for (int i = 0; i < 2; ++i) {
        int L = i * 4096 + tid * 8;                 // element index within half-tile
        int S = L ^ (((L >> 6) & 7) << 3);          // XOR cols bits 3-5 with row bits 0-2
        r_[i] = S >> 6; c_[i] = S & 63;
    }

    auto stA = [&](int buf, int h, int kt) {
#pragma unroll
        for (int i = 0; i < 2; ++i) {
            const short* src = A + (size_t)(bm + h * 128 + r_[i]) * KDIM + kt * 64 + c_[i];
            __builtin_amdgcn_global_load_lds(
                (const __attribute__((address_space(1))) void*)src,
                (__attribute__((address_space(3))) void*)&lds[buf * 16384 + h * 8192 + i * 4096 + tid * 8],
                16, 0, 0);
        }
    };
    auto stB = [&](int buf, int h, int kt) {
#pragma unroll
        for (int i = 0; i < 2; ++i) {
            const short* src = B + (size_t)(bn + h * 128 + r_[i]) * KDIM + kt * 64 + c_[i];
            __builtin_amdgcn_global_load_lds(
                (const __attribute__((address_space(1))) void*)src,
                (__attribute__((address_space(3))) void*)&lds[32768 + buf * 16384 + h * 8192 + i * 4096 + tid * 8],
                16, 0, 0);
        }
    };

    f32x4  acc[8][4] = {};
    bf16x8 bfr[4][2];
    bf16x8 afr[2][2];

    auto rdB = [&](int buf) {
        int base = 32768 + buf * 16384 + (wc * 64 + l15) * 64 + hi8;
#pragma unroll
        for (int nn = 0; nn < 4; ++nn)
#pragma unroll
            for (int k8 = 0; k8 < 2; ++k8)
                bfr[nn][k8] = *(const bf16x8*)&lds[(base + nn * 1024 + k8 * 32) ^ sx];
    };
    auto rdA = [&](int buf, int q) {
        int base = buf * 16384 + (wr * 128 + q * 32 + l15) * 64 + hi8;
#pragma unroll
        for (int mm = 0; mm < 2; ++mm)
#pragma unroll
            for (int k8 = 0; k8 < 2; ++k8)
                afr[mm][k8] = *(const bf16x8*)&lds[(base + mm * 1024 + k8 * 32) ^ sx];
    };

    // ---- prologue: A(0),B(0) -> buf0; B(1) -> buf1; wait all but B(1) ----
    stA(0, 0, 0); stA(0, 1, 0);
    stB(0, 0, 0); stB(0, 1, 0);
    stB(1, 0, 1); stB(1, 1, 1);
    asm volatile("s_waitcnt vmcnt(4)" ::: "memory");
    SBAR();

    // 32 K-tiles, 2 per iteration. Stage schedule (region freed one barrier earlier):
    // P1,P2: A(t1)->Abuf1   P3,P4: B(t2)->Bbuf0   P5,P6: A(t2)->Abuf0   P7,P8: B(t3)->Bbuf1
    // vmcnt(4) at P4/P8 leaves only the 2 newest half-tiles in flight.
    for (int i = 0; i < 16; ++i) {
        int t1 = 2 * i + 1, t2 = (2 * i + 2) & 31, t3 = (2 * i + 3) & 31;
        // P1
        rdB(0); rdA(0, 0); stA(1, 0, t1);
        SBAR(); MMQ(0); SBAR();
        // P2
        rdA(0, 1); stA(1, 1, t1);
        SBAR(); MMQ(1); SBAR();
        // P3
        rdA(0, 2); stB(0, 0, t2);
        SBAR(); MMQ(2); SBAR();
        // P4
        rdA(0, 3); stB(0, 1, t2);
        SBAR(); MMQ(3);
        asm volatile("s_waitcnt vmcnt(4)" ::: "memory");
        SBAR();
        // P5
        rdB(1); rdA(1, 0); stA(0, 0, t2);
        SBAR(); MMQ(0); SBAR();
        // P6
        rdA(1, 1); stA(0, 1, t2);
        SBAR(); MMQ(1); SBAR();
        // P7
        rdA(1, 2); stB(1, 0, t3);
        SBAR(); MMQ(2); SBAR();
        // P8
        rdA(1, 3); stB(1, 1, t3);
        SBAR(); MMQ(3);
        asm volatile("s_waitcnt vmcnt(4)" ::: "memory");
        SBAR();
    }
    asm volatile("s_waitcnt vmcnt(0)" ::: "memory");

    // epilogue: C/D layout col=lane&15, row=(lane>>4)*4+reg  [m89-verified]
    int r0 = bm + wr * 128 + (lane >> 4) * 4;
    int c0 = bn + wc * 64 + l15;
#pragma unroll
    for (int m = 0; m < 8; ++m)
#pragma unroll
        for (int nn = 0; nn < 4; ++nn)
#pragma unroll
            for (int r = 0; r < 4; ++r)
                C[(size_t)(r0 + m * 16 + r) * NDIM + c0 + nn * 16] = acc[m][nn][r];
}

extern "C" void kernel_launch(void* const* d_in, const int* in_sizes, int n_in,
                              void* d_out, int out_size, void* d_ws, size_t ws_size,
                              hipStream_t stream) {
    const float* x       = (const float*)d_in[0];   // [8192,8,256]
    const float* alpha   = (const float*)d_in[1];   // [1]
    const float* u_param = (const float*)d_in[2];   // [8,8]
    const float* T       = (const float*)d_in[3];   // [8,8,256,256]
    float* out = (float*)d_out;                     // [8192,8,256]

    short* Abf = (short*)d_ws;                                     // 32 MiB
    short* Bp  = (short*)((char*)d_ws + (size_t)BATCH * KDIM * 2); // 8 MiB

    hipLaunchKernelGGL(pack_a, dim3((BATCH * KDIM / 8) / 256), dim3(256), 0, stream, x, Abf);
    hipLaunchKernelGGL(pack_b, dim3(512), dim3(256), 0, stream, T, u_param, alpha, Bp);
    hipLaunchKernelGGL(gemm, dim3((BATCH / 256) * (NDIM / 256)), dim3(512), 0, stream,
                       Abf, Bp, out);
}